// Round 1
// baseline (68.988 us; speedup 1.0000x reference)
//
#include <hip/hip_runtime.h>
#include <hip/hip_bf16.h>

// MMD(x, w) = mean k(w,w) - 2 mean k(x,w) + mean k(x,x), RBF sigma=1.
// Combined-cloud formulation: u = [x; w], s = [-1; +1],
//   result = (sum_{i,j} s_i s_j k(u_i, u_j)) / 8192^2.
// k(a,b) = exp(-d2/2) = 2^(CEXP * d2), CEXP = -1/(2 ln 2).
// arg = CEXP*(|a|^2 + |b|^2 - 2 a.b) computed as
//   fma(ax', bx, fma(ay', by, fma(az', bz, a2c + b2c)))
// with ax' = -2*CEXP*ax, a2c = CEXP*|a|^2, b2c = CEXP*|b|^2 (staged in LDS .w).

#define NPTS       8192
#define P_TOTAL    16384
#define TILE       2048
#define BLOCK      256
#define A_PER_WAVE 8
#define A_PER_BLOCK 32            // 4 waves * 8 a-points
#define NBLOCKS    (P_TOTAL / A_PER_BLOCK)   // 512
#define CEXP       (-0.72134752044448169f)   // -1/(2 ln 2)

__device__ __forceinline__ float fast_exp2(float v) {
#if __has_builtin(__builtin_amdgcn_exp2f)
    return __builtin_amdgcn_exp2f(v);
#else
    return exp2f(v);
#endif
}

__global__ __launch_bounds__(BLOCK) void mmd_pairs(const float* __restrict__ x,
                                                   const float* __restrict__ w,
                                                   float* __restrict__ partials) {
    __shared__ float4 tile[TILE];   // 32 KB: (bx, by, bz, CEXP*|b|^2)

    const int tid  = threadIdx.x;
    const int lane = tid & 63;
    const int wave = tid >> 6;
    const int blk  = blockIdx.x;

    // This wave's 8 a-points, held uniform in VGPRs, pre-scaled.
    float axp[A_PER_WAVE], ayp[A_PER_WAVE], azp[A_PER_WAVE], a2c[A_PER_WAVE];
    const int abase = blk * A_PER_BLOCK + wave * A_PER_WAVE;
#pragma unroll
    for (int q = 0; q < A_PER_WAVE; ++q) {
        int i = abase + q;
        const float* src = (i < NPTS) ? x : w;     // uniform: 32-blocks never straddle
        int ii = i & (NPTS - 1);
        float px = src[3 * ii + 0];
        float py = src[3 * ii + 1];
        float pz = src[3 * ii + 2];
        axp[q] = (-2.0f * CEXP) * px;
        ayp[q] = (-2.0f * CEXP) * py;
        azp[q] = (-2.0f * CEXP) * pz;
        a2c[q] = CEXP * (px * px + py * py + pz * pz);
    }
    const float sa = (abase < NPTS) ? -1.0f : 1.0f;   // first half = x (sign -1)

    float acc[A_PER_WAVE];
#pragma unroll
    for (int q = 0; q < A_PER_WAVE; ++q) acc[q] = 0.0f;

    for (int t = 0; t < P_TOTAL / TILE; ++t) {
        __syncthreads();
        // Stage tile of 2048 b-points into LDS (tiles never straddle x/w boundary).
#pragma unroll
        for (int k = 0; k < TILE / BLOCK; ++k) {
            int j = t * TILE + tid + k * BLOCK;
            const float* src = (j < NPTS) ? x : w;
            int jj = j & (NPTS - 1);
            float px = src[3 * jj + 0];
            float py = src[3 * jj + 1];
            float pz = src[3 * jj + 2];
            float p2c = CEXP * (px * px + py * py + pz * pz);
            tile[tid + k * BLOCK] = make_float4(px, py, pz, p2c);
        }
        __syncthreads();

        const float st  = (t * TILE < NPTS) ? -1.0f : 1.0f;
        const float sgn = sa * st;   // uniform per (block, tile)

        for (int k = 0; k < TILE / 64; ++k) {
            float4 b = tile[k * 64 + lane];   // one ds_read_b128 per 8*64 pairs
#pragma unroll
            for (int q = 0; q < A_PER_WAVE; ++q) {
                float arg = fmaf(axp[q], b.x,
                            fmaf(ayp[q], b.y,
                            fmaf(azp[q], b.z, a2c[q] + b.w)));
                arg = fminf(arg, 0.0f);            // matches maximum(d2, 0)
                acc[q] = fmaf(sgn, fast_exp2(arg), acc[q]);
            }
        }
    }

    // Deterministic block reduction.
    float tot = 0.0f;
#pragma unroll
    for (int q = 0; q < A_PER_WAVE; ++q) tot += acc[q];
#pragma unroll
    for (int off = 32; off > 0; off >>= 1)
        tot += __shfl_xor(tot, off, 64);

    __syncthreads();                 // tile LDS reuse
    float* red = (float*)tile;
    if (lane == 0) red[wave] = tot;
    __syncthreads();
    if (tid == 0) partials[blk] = (red[0] + red[1]) + (red[2] + red[3]);
}

__global__ __launch_bounds__(256) void mmd_reduce(const float* __restrict__ partials,
                                                  float* __restrict__ out) {
    __shared__ float red[4];
    int tid = threadIdx.x;
    float v = partials[tid] + partials[tid + 256];
#pragma unroll
    for (int off = 32; off > 0; off >>= 1)
        v += __shfl_xor(v, off, 64);
    if ((tid & 63) == 0) red[tid >> 6] = v;
    __syncthreads();
    if (tid == 0)
        out[0] = ((red[0] + red[1]) + (red[2] + red[3])) * (1.0f / 67108864.0f);
}

extern "C" void kernel_launch(void* const* d_in, const int* in_sizes, int n_in,
                              void* d_out, int out_size, void* d_ws, size_t ws_size,
                              hipStream_t stream) {
    const float* x = (const float*)d_in[0];
    const float* w = (const float*)d_in[1];
    float* out      = (float*)d_out;
    float* partials = (float*)d_ws;   // NBLOCKS floats

    hipLaunchKernelGGL(mmd_pairs, dim3(NBLOCKS), dim3(BLOCK), 0, stream, x, w, partials);
    hipLaunchKernelGGL(mmd_reduce, dim3(1), dim3(256), 0, stream, partials, out);
}

// Round 2
// 32.562 us; speedup vs baseline: 2.1187x; 2.1187x over previous
//
#include <hip/hip_runtime.h>
#include <hip/hip_bf16.h>

// MMD via symmetric triangular chunk decomposition.
// u = [x; w] (16384 pts), s = [-1; +1]:
//   result = (sum_{i,j} s_i s_j k(u_i,u_j)) / 8192^2,   k = exp(-d2/2) = 2^(CEXP*d2)
// Chunks of 256 points, 64 chunks, 2080 (I>=J) chunk-pair blocks.
// Off-diagonal blocks weighted x2 (symmetry); diagonal blocks x1 (full 256x256
// computed, includes self-pairs exactly as the reference's means do).
// Per-point derived forms staged once per block in LDS:
//   A-form (SoA, packed-pair friendly): (-2C*px, -2C*py, -2C*pz, C*|p|^2)
//   B-form (AoS float4):                ( px,     py,     pz,    C*|p|^2)
// arg = fma(ax', bx, fma(ay', by, fma(az', bz, a2c + b2c)))  [<= 0 up to rounding;
// clamp dropped: max deviation ~1e-9 on the output, threshold 5.9e-6]

#define NPTS   8192
#define CH     256
#define NC     64                  // 16384 / CH
#define NXC    32                  // chunks holding x (first half)
#define NB     2080                // NC*(NC+1)/2
#define BLOCK  256
#define CEXP   (-0.72134752044448169f)     // -1/(2 ln 2)
#define M2CEXP (1.44269504088896340736f)   // -2*CEXP = 1/ln2

typedef float f32x2 __attribute__((ext_vector_type(2)));
typedef float f32x4 __attribute__((ext_vector_type(4)));

__device__ __forceinline__ f32x2 pkfma(f32x2 a, f32x2 b, f32x2 c) {
#if __has_builtin(__builtin_elementwise_fma)
    return __builtin_elementwise_fma(a, b, c);
#else
    f32x2 r; r.x = fmaf(a.x, b.x, c.x); r.y = fmaf(a.y, b.y, c.y); return r;
#endif
}

__device__ __forceinline__ float fexp2(float v) {
#if __has_builtin(__builtin_amdgcn_exp2f)
    return __builtin_amdgcn_exp2f(v);
#else
    return exp2f(v);
#endif
}

__global__ __launch_bounds__(BLOCK, 6) void mmd_tri(const float* __restrict__ x,
                                                    const float* __restrict__ w,
                                                    float* __restrict__ partials) {
    __shared__ f32x4  sAX[CH/4], sAY[CH/4], sAZ[CH/4], sA2[CH/4];  // A-form SoA
    __shared__ float4 sB[CH];                                      // B-form AoS
    __shared__ float  red[4];

    // blockIdx -> lower-triangle chunk pair (I, J), J <= I
    const int bid = blockIdx.x;
    int I = (int)((sqrtf(8.0f * (float)bid + 1.0f) - 1.0f) * 0.5f);
    while ((I + 1) * (I + 2) / 2 <= bid) ++I;
    while (I * (I + 1) / 2 > bid) --I;
    const int J = bid - I * (I + 1) / 2;

    const int tid = threadIdx.x;
    {
        int gi = I * CH + tid;                      // chunks never straddle x/w
        const float* s = (gi < NPTS) ? x : w;
        int ii = gi & (NPTS - 1);
        float px = s[3*ii], py = s[3*ii+1], pz = s[3*ii+2];
        ((float*)sAX)[tid] = M2CEXP * px;
        ((float*)sAY)[tid] = M2CEXP * py;
        ((float*)sAZ)[tid] = M2CEXP * pz;
        ((float*)sA2)[tid] = CEXP * (px*px + py*py + pz*pz);

        int gj = J * CH + tid;
        const float* t = (gj < NPTS) ? x : w;
        int jj = gj & (NPTS - 1);
        float qx = t[3*jj], qy = t[3*jj+1], qz = t[3*jj+2];
        sB[tid] = make_float4(qx, qy, qz, CEXP * (qx*qx + qy*qy + qz*qz));
    }
    __syncthreads();

    const int lane = tid & 63;
    const int wave = tid >> 6;

    float acc[8];
#pragma unroll
    for (int q = 0; q < 8; ++q) acc[q] = 0.0f;

#pragma unroll 1
    for (int ai = 0; ai < CH / 32; ++ai) {          // 8 a-iters, 8 a's per wave
        const int a4 = (ai * 32 + wave * 8) >> 2;   // index into f32x4 SoA
        f32x4 ax0 = sAX[a4], ax1 = sAX[a4 + 1];
        f32x4 ay0 = sAY[a4], ay1 = sAY[a4 + 1];
        f32x4 az0 = sAZ[a4], az1 = sAZ[a4 + 1];
        f32x4 a20 = sA2[a4], a21 = sA2[a4 + 1];
        // q-pairs as aligned subregisters (no movs)
        f32x2 axp[4] = { ax0.xy, ax0.zw, ax1.xy, ax1.zw };
        f32x2 ayp[4] = { ay0.xy, ay0.zw, ay1.xy, ay1.zw };
        f32x2 azp[4] = { az0.xy, az0.zw, az1.xy, az1.zw };
        f32x2 a2p[4] = { a20.xy, a20.zw, a21.xy, a21.zw };

#pragma unroll
        for (int k = 0; k < CH / 64; ++k) {         // each lane: 1 b-point per k
            float4 b = sB[k * 64 + lane];           // one ds_read_b128 / 512 pairs
            f32x2 bxx = { b.x, b.x };               // 4 splats per 512 pairs
            f32x2 byy = { b.y, b.y };
            f32x2 bzz = { b.z, b.z };
            f32x2 bww = { b.w, b.w };
#pragma unroll
            for (int p = 0; p < 4; ++p) {
                f32x2 arg = pkfma(axp[p], bxx,
                            pkfma(ayp[p], byy,
                            pkfma(azp[p], bzz, a2p[p] + bww)));
                acc[2*p]     += fexp2(arg.x);
                acc[2*p + 1] += fexp2(arg.y);
            }
        }
    }

    float tot = 0.0f;
#pragma unroll
    for (int q = 0; q < 8; ++q) tot += acc[q];
#pragma unroll
    for (int off = 32; off > 0; off >>= 1)
        tot += __shfl_xor(tot, off, 64);

    if (lane == 0) red[wave] = tot;
    __syncthreads();
    if (tid == 0) {
        const float sa = (I < NXC) ? -1.0f : 1.0f;
        const float sb = (J < NXC) ? -1.0f : 1.0f;
        const float wt = (I == J) ? 1.0f : 2.0f;
        partials[bid] = (sa * sb * wt) * ((red[0] + red[1]) + (red[2] + red[3]));
    }
}

__global__ __launch_bounds__(256) void mmd_reduce(const float* __restrict__ partials,
                                                  float* __restrict__ out) {
    __shared__ float red[4];
    const int tid = threadIdx.x;
    float v = 0.0f;
    for (int i = tid; i < NB; i += 256) v += partials[i];
#pragma unroll
    for (int off = 32; off > 0; off >>= 1)
        v += __shfl_xor(v, off, 64);
    if ((tid & 63) == 0) red[tid >> 6] = v;
    __syncthreads();
    if (tid == 0)
        out[0] = ((red[0] + red[1]) + (red[2] + red[3])) * (1.0f / 67108864.0f);
}

extern "C" void kernel_launch(void* const* d_in, const int* in_sizes, int n_in,
                              void* d_out, int out_size, void* d_ws, size_t ws_size,
                              hipStream_t stream) {
    const float* x = (const float*)d_in[0];
    const float* w = (const float*)d_in[1];
    float* out      = (float*)d_out;
    float* partials = (float*)d_ws;   // NB floats = 8320 B

    hipLaunchKernelGGL(mmd_tri, dim3(NB), dim3(BLOCK), 0, stream, x, w, partials);
    hipLaunchKernelGGL(mmd_reduce, dim3(1), dim3(256), 0, stream, partials, out);
}

// Round 3
// 30.606 us; speedup vs baseline: 2.2541x; 1.0639x over previous
//
#include <hip/hip_runtime.h>
#include <hip/hip_bf16.h>

// MMD via symmetric triangular chunk decomposition.
// u = [x; w] (16384 pts), s = [-1; +1]:
//   result = (sum_{i,j} s_i s_j k(u_i,u_j)) / 8192^2,   k = exp(-d2/2) = 2^(CEXP*d2)
// Chunks of 256 points, 64 chunks, 2080 (I>=J) chunk-pair blocks; off-diagonal x2.
// Per-point derived forms staged once per block in LDS:
//   A-form (SoA f32x4): (-2C*px, -2C*py, -2C*pz, C*|p|^2)  -> packed-pair operands
//   B-form (AoS float4): (px, py, pz, C*|p|^2)
// arg = pkfma(ax', bx, pkfma(ay', by, pkfma(az', bz, a2c + b2c)))  [<=0 up to
// rounding; clamp dropped: deviation ~1e-9 on output vs 5.9e-6 threshold]
// exp2 is forced to a single v_exp_f32 (builtin or inline asm) -- never libm.

#define NPTS   8192
#define CH     256
#define NC     64                  // 16384 / CH
#define NXC    32                  // chunks holding x (first half)
#define NB     2080                // NC*(NC+1)/2
#define BLOCK  256
#define CEXP   (-0.72134752044448169f)     // -1/(2 ln 2)
#define M2CEXP (1.44269504088896340736f)   // -2*CEXP = 1/ln2

typedef float f32x2 __attribute__((ext_vector_type(2)));
typedef float f32x4 __attribute__((ext_vector_type(4)));

__device__ __forceinline__ f32x2 pkfma(f32x2 a, f32x2 b, f32x2 c) {
#if __has_builtin(__builtin_elementwise_fma)
    return __builtin_elementwise_fma(a, b, c);
#else
    f32x2 r; r.x = fmaf(a.x, b.x, c.x); r.y = fmaf(a.y, b.y, c.y); return r;
#endif
}

// Single-instruction 2^x. CDNA VGPR RAW hazards are HW-interlocked, so the
// inline-asm fallback needs no manual wait states.
__device__ __forceinline__ float fexp2(float v) {
#if __has_builtin(__builtin_amdgcn_exp2f)
    return __builtin_amdgcn_exp2f(v);
#else
    float r;
    asm("v_exp_f32 %0, %1" : "=v"(r) : "v"(v));
    return r;
#endif
}

__global__ __launch_bounds__(BLOCK, 6) void mmd_tri(const float* __restrict__ x,
                                                    const float* __restrict__ w,
                                                    float* __restrict__ partials) {
    __shared__ f32x4  sAX[CH/4], sAY[CH/4], sAZ[CH/4], sA2[CH/4];  // A-form SoA
    __shared__ float4 sB[CH];                                      // B-form AoS
    __shared__ float  red[4];

    // blockIdx -> lower-triangle chunk pair (I, J), J <= I
    const int bid = blockIdx.x;
    int I = (int)((sqrtf(8.0f * (float)bid + 1.0f) - 1.0f) * 0.5f);
    while ((I + 1) * (I + 2) / 2 <= bid) ++I;
    while (I * (I + 1) / 2 > bid) --I;
    const int J = bid - I * (I + 1) / 2;

    const int tid = threadIdx.x;
    {
        int gi = I * CH + tid;                      // chunks never straddle x/w
        const float* s = (gi < NPTS) ? x : w;
        int ii = gi & (NPTS - 1);
        float px = s[3*ii], py = s[3*ii+1], pz = s[3*ii+2];
        ((float*)sAX)[tid] = M2CEXP * px;
        ((float*)sAY)[tid] = M2CEXP * py;
        ((float*)sAZ)[tid] = M2CEXP * pz;
        ((float*)sA2)[tid] = CEXP * (px*px + py*py + pz*pz);

        int gj = J * CH + tid;
        const float* t = (gj < NPTS) ? x : w;
        int jj = gj & (NPTS - 1);
        float qx = t[3*jj], qy = t[3*jj+1], qz = t[3*jj+2];
        sB[tid] = make_float4(qx, qy, qz, CEXP * (qx*qx + qy*qy + qz*qz));
    }
    __syncthreads();

    const int lane = tid & 63;
    const int wave = tid >> 6;

    f32x2 acc2[4];
#pragma unroll
    for (int p = 0; p < 4; ++p) acc2[p] = (f32x2){0.0f, 0.0f};

#pragma unroll 1
    for (int ai = 0; ai < CH / 32; ++ai) {          // 8 a-iters, 8 a's per wave
        const int a4 = (ai * 32 + wave * 8) >> 2;   // index into f32x4 SoA
        f32x4 ax0 = sAX[a4], ax1 = sAX[a4 + 1];
        f32x4 ay0 = sAY[a4], ay1 = sAY[a4 + 1];
        f32x4 az0 = sAZ[a4], az1 = sAZ[a4 + 1];
        f32x4 a20 = sA2[a4], a21 = sA2[a4 + 1];
        // q-pairs as even-aligned subregisters of the x4 loads (no movs)
        f32x2 axp[4] = { ax0.xy, ax0.zw, ax1.xy, ax1.zw };
        f32x2 ayp[4] = { ay0.xy, ay0.zw, ay1.xy, ay1.zw };
        f32x2 azp[4] = { az0.xy, az0.zw, az1.xy, az1.zw };
        f32x2 a2p[4] = { a20.xy, a20.zw, a21.xy, a21.zw };

#pragma unroll
        for (int k = 0; k < CH / 64; ++k) {         // each lane: 1 b-point per k
            float4 b = sB[k * 64 + lane];           // one ds_read_b128 / 512 pairs
            f32x2 bxx = { b.x, b.x };
            f32x2 byy = { b.y, b.y };
            f32x2 bzz = { b.z, b.z };
            f32x2 bww = { b.w, b.w };
#pragma unroll
            for (int p = 0; p < 4; ++p) {
                f32x2 arg = pkfma(axp[p], bxx,
                            pkfma(ayp[p], byy,
                            pkfma(azp[p], bzz, a2p[p] + bww)));
                f32x2 ev;
                ev.x = fexp2(arg.x);
                ev.y = fexp2(arg.y);
                acc2[p] += ev;                       // v_pk_add_f32
            }
        }
    }

    float tot = 0.0f;
#pragma unroll
    for (int p = 0; p < 4; ++p) tot += acc2[p].x + acc2[p].y;
#pragma unroll
    for (int off = 32; off > 0; off >>= 1)
        tot += __shfl_xor(tot, off, 64);

    if (lane == 0) red[wave] = tot;
    __syncthreads();
    if (tid == 0) {
        const float sa = (I < NXC) ? -1.0f : 1.0f;
        const float sb = (J < NXC) ? -1.0f : 1.0f;
        const float wt = (I == J) ? 1.0f : 2.0f;
        partials[bid] = (sa * sb * wt) * ((red[0] + red[1]) + (red[2] + red[3]));
    }
}

__global__ __launch_bounds__(256) void mmd_reduce(const float* __restrict__ partials,
                                                  float* __restrict__ out) {
    __shared__ float red[4];
    const int tid = threadIdx.x;
    float v = 0.0f;
    for (int i = tid; i < NB; i += 256) v += partials[i];
#pragma unroll
    for (int off = 32; off > 0; off >>= 1)
        v += __shfl_xor(v, off, 64);
    if ((tid & 63) == 0) red[tid >> 6] = v;
    __syncthreads();
    if (tid == 0)
        out[0] = ((red[0] + red[1]) + (red[2] + red[3])) * (1.0f / 67108864.0f);
}

extern "C" void kernel_launch(void* const* d_in, const int* in_sizes, int n_in,
                              void* d_out, int out_size, void* d_ws, size_t ws_size,
                              hipStream_t stream) {
    const float* x = (const float*)d_in[0];
    const float* w = (const float*)d_in[1];
    float* out      = (float*)d_out;
    float* partials = (float*)d_ws;   // NB floats = 8320 B

    hipLaunchKernelGGL(mmd_tri, dim3(NB), dim3(BLOCK), 0, stream, x, w, partials);
    hipLaunchKernelGGL(mmd_reduce, dim3(1), dim3(256), 0, stream, partials, out);
}